// Round 9
// baseline (90.688 us; speedup 1.0000x reference)
//
#include <hip/hip_runtime.h>

#define NN 8192
#define DD 256    // 512 bytes per bf16 row
#define NT 8256   // 128*129/2 lower-triangle 64x64 tiles
#define NBLK 4128 // 2 tiles per 1-wave block, exact

typedef __bf16 bf16x8 __attribute__((ext_vector_type(8)));
typedef float  f32x4  __attribute__((ext_vector_type(4)));

__device__ __forceinline__ unsigned short f2bf(float f) {
    unsigned u = __float_as_uint(f);
    return (unsigned short)((u + 0x7fffu + ((u >> 16) & 1u)) >> 16);
}

__device__ __forceinline__ void gload16(const void* g, void* l) {
    __builtin_amdgcn_global_load_lds((const __attribute__((address_space(1))) void*)g,
                                     (__attribute__((address_space(3))) void*)l,
                                     16, 0, 0);
}

// ---------------- kernel 1: normalize rows -> bf16, zero accumulators ----------------
__global__ __launch_bounds__(256) void ntxent_norm(const float* __restrict__ z,
                                                   char* __restrict__ znB,
                                                   float* __restrict__ rowsum,
                                                   float* __restrict__ possum)
{
    const int t = threadIdx.x;
    const int l = t & 63;
    const int w = t >> 6;
    const int row = blockIdx.x * 4 + w;

    float4 v = ((const float4*)(z + (size_t)row * DD))[l];
    float ss = v.x * v.x + v.y * v.y + v.z * v.z + v.w * v.w;
    ss += __shfl_xor(ss, 1);  ss += __shfl_xor(ss, 2);  ss += __shfl_xor(ss, 4);
    ss += __shfl_xor(ss, 8);  ss += __shfl_xor(ss, 16); ss += __shfl_xor(ss, 32);
    const float inv = 1.0f / fmaxf(sqrtf(ss), 1e-8f);

    uint2 o;
    o.x = (unsigned)f2bf(v.x * inv) | ((unsigned)f2bf(v.y * inv) << 16);
    o.y = (unsigned)f2bf(v.z * inv) | ((unsigned)f2bf(v.w * inv) << 16);
    ((uint2*)(znB + (size_t)row * 512))[l] = o;

    if (blockIdx.x < 32) rowsum[blockIdx.x * 256 + t] = 0.0f;
    if (blockIdx.x == 32 && t == 0) possum[0] = 0.0f;
}

// ---------------- kernel 2: barrier-free per-wave 64x64 symmetric triangle ----------------
// One wave (64-thr block) owns a whole 64x64 tile: acc[4][4] frags, private 16 KB LDS
// (A 8 KB + B 8 KB per BK=64 chunk). Staging ordered by the wave's OWN vmcnt/lgkmcnt —
// no __syncthreads anywhere, so the CU scheduler freely interleaves 10 resident waves.
// Geometry/swizzle/fragment reads = R1's proven machinery (0 bank conflicts measured).
// Off-diag tile feeds rowsum_i (row reduce) and rowsum_j (col reduce); diag: self-mask
// + positive pairs. 4128 blocks x exactly 2 triangle tiles each.
__global__ __launch_bounds__(64) void ntxent_sim(const char* __restrict__ znB,
                                                 float* __restrict__ rowsum,
                                                 float* __restrict__ possum)
{
    __shared__ char sAB[16384];   // [A: 64 rows x 128B | B: 64 rows x 128B], XOR-swizzled

    const int l  = threadIdx.x;
    const int lm = l & 15;
    const int lh = l >> 4;       // 0..3

    const int t0 = blockIdx.x * 2;

    // t0 -> (r, c), r >= c  (triangle)
    int r = (int)((sqrtf(8.0f * (float)t0 + 1.0f) - 1.0f) * 0.5f);
    while ((r + 1) * (r + 2) / 2 <= t0) ++r;
    while (r * (r + 1) / 2 > t0) --r;
    int c = t0 - r * (r + 1) / 2;

    // stage chunk bk (BK=64: 128 B per row) of tile (rowbase,colbase): 16 x gload16
    auto STAGE = [&](int rowbase, int colbase, int bk) {
#pragma unroll
        for (int p = 0; p < 8; ++p) {
            const int flat = p * 1024 + l * 16;
            const int row  = flat >> 7;                       // 0..63
            const int kb   = (flat & 127) ^ ((row & 7) << 4); // pre-swizzled source
            gload16(znB + (size_t)(rowbase + row) * 512 + bk * 128 + kb, sAB + flat);
            gload16(znB + (size_t)(colbase + row) * 512 + bk * 128 + kb, sAB + 8192 + flat);
        }
    };

    STAGE(r * 64, c * 64, 0);

    const f32x4 vzero = {0.0f, 0.0f, 0.0f, 0.0f};

#pragma unroll 1
    for (int tl = 0; tl < 2; ++tl) {
        const int rowbase = r * 64;
        const int colbase = c * 64;
        const bool diag = (r == c);
        const int nr = (c < r) ? r : r + 1;   // next triangle tile
        const int nc = (c < r) ? c + 1 : 0;

        f32x4 acc[4][4];
#pragma unroll
        for (int i = 0; i < 4; ++i)
#pragma unroll
            for (int j = 0; j < 4; ++j) acc[i][j] = vzero;

#pragma unroll 1
        for (int bk = 0; bk < 4; ++bk) {
            asm volatile("s_waitcnt vmcnt(0)" ::: "memory");  // my chunk landed
#pragma unroll
            for (int kw = 0; kw < 2; ++kw) {
                const int kt = kw * 64 + lh * 16;
                bf16x8 af[4], bfr[4];
#pragma unroll
                for (int s = 0; s < 4; ++s) {
                    const int ar = s * 16 + lm;
                    af[s]  = *(const bf16x8*)(sAB + ar * 128 + (kt ^ ((ar & 7) << 4)));
                    bfr[s] = *(const bf16x8*)(sAB + 8192 + ar * 128 + (kt ^ ((ar & 7) << 4)));
                }
#pragma unroll
                for (int i = 0; i < 4; ++i)
#pragma unroll
                    for (int j = 0; j < 4; ++j)
                        acc[i][j] = __builtin_amdgcn_mfma_f32_16x16x32_bf16(af[i], bfr[j], acc[i][j], 0, 0, 0);
            }
            // reads done -> safe to overwrite my private LDS; stage flies under MFMA/epilogue
            asm volatile("s_waitcnt lgkmcnt(0)" ::: "memory");
            if (bk < 3)        STAGE(rowbase, colbase, bk + 1);
            else if (tl == 0)  STAGE(nr * 64, nc * 64, 0);
        }

        // ---------------- epilogue: exp, row sums, col sums (symmetry), positives ----
        float rsum[16];
#pragma unroll
        for (int q = 0; q < 16; ++q) rsum[q] = 0.0f;
        float csum[4] = {0.0f, 0.0f, 0.0f, 0.0f};
        float psum = 0.0f;

#pragma unroll
        for (int i = 0; i < 4; ++i) {
            const int ib = rowbase + i * 16 + lh * 4;
#pragma unroll
            for (int j = 0; j < 4; ++j) {
                const int jc = colbase + j * 16 + lm;
#pragma unroll
                for (int q = 0; q < 4; ++q) {
                    const int ii = ib + q;
                    const float lg = 2.0f * acc[i][j][q];
                    const float e = __expf(lg);
                    const float ev = (diag && (jc == ii)) ? 0.0f : e;
                    rsum[i * 4 + q] += ev;
                    csum[j] += ev;                                  // used iff !diag
                    if (diag) psum += (jc == (ii ^ 1)) ? lg : 0.0f;
                }
            }
        }

        // row sums: reduce over 16 lm lanes, atomics from lm==0 lanes
#pragma unroll
        for (int q = 0; q < 16; ++q) {
            float v = rsum[q];
            v += __shfl_xor(v, 1); v += __shfl_xor(v, 2);
            v += __shfl_xor(v, 4); v += __shfl_xor(v, 8);
            rsum[q] = v;
        }
        if (lm == 0) {
#pragma unroll
            for (int i = 0; i < 4; ++i)
#pragma unroll
                for (int q = 0; q < 4; ++q)
                    atomicAdd(&rowsum[rowbase + i * 16 + lh * 4 + q], rsum[i * 4 + q]);
        }

        if (!diag) {
            // col sums (transposed contribution): collapse lh, atomics from lh==0 lanes
#pragma unroll
            for (int j = 0; j < 4; ++j) {
                float v = csum[j];
                v += __shfl_xor(v, 16); v += __shfl_xor(v, 32);
                if (lh == 0) atomicAdd(&rowsum[colbase + j * 16 + lm], v);
            }
        } else {
            float p = psum;
            p += __shfl_xor(p, 1);  p += __shfl_xor(p, 2);  p += __shfl_xor(p, 4);
            p += __shfl_xor(p, 8);  p += __shfl_xor(p, 16); p += __shfl_xor(p, 32);
            if (l == 0) atomicAdd(possum, p);
        }

        r = nr; c = nc;
    }
}

// ---------------- kernel 3: final scalar ----------------
__global__ __launch_bounds__(512) void ntxent_final(const float* __restrict__ rowsum,
                                                    const float* __restrict__ possum,
                                                    float* __restrict__ out)
{
    __shared__ float sh[8];
    const int t = threadIdx.x;
    float s = 0.0f;
#pragma unroll
    for (int r = 0; r < 16; ++r) s += __logf(rowsum[r * 512 + t]);  // ILP: 16 indep loads
    s += __shfl_xor(s, 1);  s += __shfl_xor(s, 2);  s += __shfl_xor(s, 4);
    s += __shfl_xor(s, 8);  s += __shfl_xor(s, 16); s += __shfl_xor(s, 32);
    if ((t & 63) == 0) sh[t >> 6] = s;
    __syncthreads();
    if (t == 0) {
        float a = 0.0f;
#pragma unroll
        for (int k = 0; k < 8; ++k) a += sh[k];
        out[0] = (a - possum[0]) * (1.0f / NN);
    }
}

extern "C" void kernel_launch(void* const* d_in, const int* in_sizes, int n_in,
                              void* d_out, int out_size, void* d_ws, size_t ws_size,
                              hipStream_t stream)
{
    const float* z = (const float*)d_in[0];
    char*  znB    = (char*)d_ws;
    float* rowsum = (float*)((char*)d_ws + (size_t)NN * 512);
    float* possum = (float*)((char*)d_ws + (size_t)NN * 512 + (size_t)NN * 4);
    float* out = (float*)d_out;

    ntxent_norm <<<dim3(NN / 4), dim3(256), 0, stream>>>(z, znB, rowsum, possum);
    ntxent_sim  <<<dim3(NBLK),   dim3(64),  0, stream>>>(znB, rowsum, possum);
    ntxent_final<<<dim3(1),      dim3(512), 0, stream>>>(rowsum, possum, out);
}

// Round 10
// 70.492 us; speedup vs baseline: 1.2865x; 1.2865x over previous
//
#include <hip/hip_runtime.h>

#define NN 8192
#define DD 256    // 512 bytes per bf16 row
#define NTILES 2080
#define NBLK 520  // 4 triangle tiles per block, exact

typedef __bf16 bf16x8 __attribute__((ext_vector_type(8)));
typedef float  f32x4  __attribute__((ext_vector_type(4)));

__device__ __forceinline__ unsigned short f2bf(float f) {
    unsigned u = __float_as_uint(f);
    return (unsigned short)((u + 0x7fffu + ((u >> 16) & 1u)) >> 16);
}

__device__ __forceinline__ void gload16(const void* g, void* l) {
    __builtin_amdgcn_global_load_lds((const __attribute__((address_space(1))) void*)g,
                                     (__attribute__((address_space(3))) void*)l,
                                     16, 0, 0);
}

// ---------------- kernel 1: normalize rows -> bf16, zero accumulators ----------------
__global__ __launch_bounds__(256) void ntxent_norm(const float* __restrict__ z,
                                                   char* __restrict__ znB,
                                                   float* __restrict__ rowsum,
                                                   float* __restrict__ possum)
{
    const int t = threadIdx.x;
    const int l = t & 63;
    const int w = t >> 6;
    const int row = blockIdx.x * 4 + w;

    float4 v = ((const float4*)(z + (size_t)row * DD))[l];
    float ss = v.x * v.x + v.y * v.y + v.z * v.z + v.w * v.w;
    ss += __shfl_xor(ss, 1);  ss += __shfl_xor(ss, 2);  ss += __shfl_xor(ss, 4);
    ss += __shfl_xor(ss, 8);  ss += __shfl_xor(ss, 16); ss += __shfl_xor(ss, 32);
    const float inv = 1.0f / fmaxf(sqrtf(ss), 1e-8f);

    uint2 o;
    o.x = (unsigned)f2bf(v.x * inv) | ((unsigned)f2bf(v.y * inv) << 16);
    o.y = (unsigned)f2bf(v.z * inv) | ((unsigned)f2bf(v.w * inv) << 16);
    ((uint2*)(znB + (size_t)row * 512))[l] = o;

    if (blockIdx.x < 32) rowsum[blockIdx.x * 256 + t] = 0.0f;
    if (blockIdx.x == 32 && t == 0) possum[0] = 0.0f;
}

// ---------------- kernel 2: 8-wave low-register symmetric triangle GEMM + exp ----------
// 2080 lower-triangle 128x128 tiles, 520 blocks x 4 tiles (uniform, 16 K-steps/block).
// 512 threads = 8 waves: wave tile 64x32 -> acc[4][2] (32 AGPR) + af[4]/bfr[2] (24 VGPR)
// => ~110 unified regs/wave -> 4 waves/SIMD resident (2 blocks/CU), double R1's
// concurrency, which is the only variable that has moved throughput in 9 rounds.
// K-step machinery = R1's proven 2-barrier BK=64 XOR-swizzled layout (0 conflicts).
// Off-diag tile feeds rowsum_i (row reduce) AND rowsum_j (col reduce); diag: self-mask
// + positive pairs. __launch_bounds__(512,4) caps unified regs at 128 (> natural need).
__global__ __launch_bounds__(512, 4) void ntxent_sim(const char* __restrict__ znB,
                                                     float* __restrict__ rowsum,
                                                     float* __restrict__ possum)
{
    __shared__ char sA[16384];   // 128 rows x 128B (BK=64 bf16), XOR-swizzled
    __shared__ char sB[16384];

    const int t  = threadIdx.x;
    const int l  = t & 63;
    const int w  = t >> 6;      // wave 0..7
    const int wr = w >> 2;      // row half (64 rows)
    const int wc = w & 3;       // col quarter (32 cols)
    const int lm = l & 15;
    const int lh = l >> 4;      // 0..3

    const int arow0 = wr * 64;
    const int bcol0 = wc * 32;
    const f32x4 vzero = {0.0f, 0.0f, 0.0f, 0.0f};

    // first tile of this block's run of 4
    const int t0 = blockIdx.x * 4;
    int rt = (int)((sqrtf(8.0f * (float)t0 + 1.0f) - 1.0f) * 0.5f);
    while ((rt + 1) * (rt + 2) / 2 <= t0) ++rt;
    while (rt * (rt + 1) / 2 > t0) --rt;
    int ct = t0 - rt * (rt + 1) / 2;

#pragma unroll 1
    for (int tl = 0; tl < 4; ++tl) {
        const int rowbase = rt * 128;
        const int colbase = ct * 128;
        const bool diag = (rt == ct);

        f32x4 acc[4][2];
#pragma unroll
        for (int s = 0; s < 4; ++s) { acc[s][0] = vzero; acc[s][1] = vzero; }

#pragma unroll 1
        for (int bk = 0; bk < 4; ++bk) {
            __syncthreads();   // all waves done reading sA/sB from previous step
            // stage A and B tiles (16 KB each) with 512 threads: 2 gload16 per array
#pragma unroll
            for (int p = 0; p < 2; ++p) {
                const int flat = p * 8192 + t * 16;
                const int row = flat >> 7;
                const int skb = (flat & 127) ^ ((row & 7) << 4);
                gload16(znB + (size_t)(rowbase + row) * 512 + bk * 128 + skb, sA + flat);
                gload16(znB + (size_t)(colbase + row) * 512 + bk * 128 + skb, sB + flat);
            }
            asm volatile("s_waitcnt vmcnt(0)" ::: "memory");
            __syncthreads();
#pragma unroll
            for (int kw = 0; kw < 2; ++kw) {
                const int kt = kw * 64 + lh * 16;   // byte offset within BK chunk
                bf16x8 af[4], bfr[2];
#pragma unroll
                for (int s = 0; s < 4; ++s) {
                    const int ar = arow0 + s * 16 + lm;
                    af[s] = *(const bf16x8*)(sA + ar * 128 + (kt ^ ((ar & 7) << 4)));
                }
#pragma unroll
                for (int c = 0; c < 2; ++c) {
                    const int bc = bcol0 + c * 16 + lm;
                    bfr[c] = *(const bf16x8*)(sB + bc * 128 + (kt ^ ((bc & 7) << 4)));
                }
#pragma unroll
                for (int s = 0; s < 4; ++s) {
                    acc[s][0] = __builtin_amdgcn_mfma_f32_16x16x32_bf16(af[s], bfr[0], acc[s][0], 0, 0, 0);
                    acc[s][1] = __builtin_amdgcn_mfma_f32_16x16x32_bf16(af[s], bfr[1], acc[s][1], 0, 0, 0);
                }
            }
        }

        // ---------------- epilogue: exp, row sums, col sums (symmetry), positives ----
        float rsum[16];
#pragma unroll
        for (int q = 0; q < 16; ++q) rsum[q] = 0.0f;
        float csum[2] = {0.0f, 0.0f};
        float psum = 0.0f;

#pragma unroll
        for (int s = 0; s < 4; ++s) {
            const int ib = rowbase + arow0 + s * 16 + lh * 4;
#pragma unroll
            for (int c = 0; c < 2; ++c) {
                const int j = colbase + bcol0 + c * 16 + lm;
#pragma unroll
                for (int q = 0; q < 4; ++q) {
                    const int i = ib + q;
                    const float lg = 2.0f * acc[s][c][q];
                    const float e = __expf(lg);
                    const float ev = (diag && (j == i)) ? 0.0f : e;
                    rsum[s * 4 + q] += ev;
                    csum[c] += ev;                                   // used iff !diag
                    if (diag) psum += (j == (i ^ 1)) ? lg : 0.0f;
                }
            }
        }

        // row sums: reduce over the 16 lm lanes, one atomic per row (lm==0)
#pragma unroll
        for (int q = 0; q < 16; ++q) {
            float v = rsum[q];
            v += __shfl_xor(v, 1); v += __shfl_xor(v, 2);
            v += __shfl_xor(v, 4); v += __shfl_xor(v, 8);
            rsum[q] = v;
        }
        if (lm == 0) {
#pragma unroll
            for (int s = 0; s < 4; ++s)
#pragma unroll
                for (int q = 0; q < 4; ++q)
                    atomicAdd(&rowsum[rowbase + arow0 + s * 16 + lh * 4 + q], rsum[s * 4 + q]);
        }

        if (!diag) {
            // col sums (transposed contribution): collapse lh, one atomic per col (lh==0)
#pragma unroll
            for (int c = 0; c < 2; ++c) {
                float v = csum[c];
                v += __shfl_xor(v, 16); v += __shfl_xor(v, 32);
                if (lh == 0) atomicAdd(&rowsum[colbase + bcol0 + c * 16 + lm], v);
            }
        } else {
            float p = psum;
            p += __shfl_xor(p, 1);  p += __shfl_xor(p, 2);  p += __shfl_xor(p, 4);
            p += __shfl_xor(p, 8);  p += __shfl_xor(p, 16); p += __shfl_xor(p, 32);
            if (l == 0) atomicAdd(possum, p);
        }

        // next triangle tile
        const int nrt = (ct < rt) ? rt : rt + 1;
        const int nct = (ct < rt) ? ct + 1 : 0;
        rt = nrt; ct = nct;
    }
}

// ---------------- kernel 3: final scalar ----------------
__global__ __launch_bounds__(512) void ntxent_final(const float* __restrict__ rowsum,
                                                    const float* __restrict__ possum,
                                                    float* __restrict__ out)
{
    __shared__ float sh[8];
    const int t = threadIdx.x;
    float s = 0.0f;
#pragma unroll
    for (int r = 0; r < 16; ++r) s += __logf(rowsum[r * 512 + t]);  // ILP: 16 indep loads
    s += __shfl_xor(s, 1);  s += __shfl_xor(s, 2);  s += __shfl_xor(s, 4);
    s += __shfl_xor(s, 8);  s += __shfl_xor(s, 16); s += __shfl_xor(s, 32);
    if ((t & 63) == 0) sh[t >> 6] = s;
    __syncthreads();
    if (t == 0) {
        float a = 0.0f;
#pragma unroll
        for (int k = 0; k < 8; ++k) a += sh[k];
        out[0] = (a - possum[0]) * (1.0f / NN);
    }
}

extern "C" void kernel_launch(void* const* d_in, const int* in_sizes, int n_in,
                              void* d_out, int out_size, void* d_ws, size_t ws_size,
                              hipStream_t stream)
{
    const float* z = (const float*)d_in[0];
    char*  znB    = (char*)d_ws;
    float* rowsum = (float*)((char*)d_ws + (size_t)NN * 512);
    float* possum = (float*)((char*)d_ws + (size_t)NN * 512 + (size_t)NN * 4);
    float* out = (float*)d_out;

    ntxent_norm <<<dim3(NN / 4), dim3(256), 0, stream>>>(z, znB, rowsum, possum);
    ntxent_sim  <<<dim3(NBLK),   dim3(512), 0, stream>>>(znB, rowsum, possum);
    ntxent_final<<<dim3(1),      dim3(512), 0, stream>>>(rowsum, possum, out);
}

// Round 11
// 60.604 us; speedup vs baseline: 1.4964x; 1.1632x over previous
//
#include <hip/hip_runtime.h>

#define NN 8192
#define DD 256   // 512 bytes per bf16 row

typedef __bf16 bf16x8 __attribute__((ext_vector_type(8)));
typedef float  f32x4  __attribute__((ext_vector_type(4)));

__device__ __forceinline__ unsigned short f2bf(float f) {
    unsigned u = __float_as_uint(f);
    return (unsigned short)((u + 0x7fffu + ((u >> 16) & 1u)) >> 16);
}

__device__ __forceinline__ void gload16(const void* g, void* l) {
    __builtin_amdgcn_global_load_lds((const __attribute__((address_space(1))) void*)g,
                                     (__attribute__((address_space(3))) void*)l,
                                     16, 0, 0);
}

// ---------------- kernel 1: normalize rows -> bf16, zero accumulators ----------------
__global__ __launch_bounds__(256) void ntxent_norm(const float* __restrict__ z,
                                                   char* __restrict__ znB,
                                                   float* __restrict__ rowsum,
                                                   float* __restrict__ possum)
{
    const int t = threadIdx.x;
    const int l = t & 63;
    const int w = t >> 6;
    const int row = blockIdx.x * 4 + w;

    float4 v = ((const float4*)(z + (size_t)row * DD))[l];
    float ss = v.x * v.x + v.y * v.y + v.z * v.z + v.w * v.w;
    ss += __shfl_xor(ss, 1);  ss += __shfl_xor(ss, 2);  ss += __shfl_xor(ss, 4);
    ss += __shfl_xor(ss, 8);  ss += __shfl_xor(ss, 16); ss += __shfl_xor(ss, 32);
    const float inv = 1.0f / fmaxf(sqrtf(ss), 1e-8f);

    uint2 o;
    o.x = (unsigned)f2bf(v.x * inv) | ((unsigned)f2bf(v.y * inv) << 16);
    o.y = (unsigned)f2bf(v.z * inv) | ((unsigned)f2bf(v.w * inv) << 16);
    ((uint2*)(znB + (size_t)row * 512))[l] = o;

    if (blockIdx.x < 32) rowsum[blockIdx.x * 256 + t] = 0.0f;
    if (blockIdx.x == 32 && t == 0) possum[0] = 0.0f;
}

// ---------------- kernel 2: triangle-pruned R1 (block = (rt, js), js <= rt/4) --------
// R1's exact machinery: 256 thr / 4 waves / 64x64 wave tiles, 512-col j-walk (up to 4
// j-tiles x 4 bk = 16 K-steps), 2-barrier XOR-swizzled staging (0 conflicts measured),
// rsum[16] accumulated in REGISTERS across the whole block, ONE heavy 64-shfl row
// reduce + row atomics per block (the R6/R7 per-tile reduce cadence was the 0.80 ->
// 1.40 us/step regression). Triangle pruning: only j-tiles with jcb <= rowbase are
// computed; off-diag tiles also flush a cheap per-tile col-reduce (csum[4]: 2 shfl +
// 1 atomic each) for the transposed contribution; diag tiles self-mask + positives.
// Grid: 544 blocks = sum over 4-row bands g of 4*(g+1); exactly 2080 tiles, no pad.
__global__ __launch_bounds__(256) void ntxent_sim(const char* __restrict__ znB,
                                                  float* __restrict__ rowsum,
                                                  float* __restrict__ possum)
{
    __shared__ char sA[16384];   // 128 rows x 128B (BK=64 bf16), XOR-swizzled
    __shared__ char sB[16384];
    __shared__ float psh[4];

    const int t  = threadIdx.x;
    const int l  = t & 63;
    const int w  = t >> 6;      // wave 0..3
    const int wr = w >> 1;      // row half
    const int wc = w & 1;       // col half
    const int lm = l & 15;
    const int lh = l >> 4;      // 0..3

    // bid -> (rt, js): band g = rt>>2 spans 4*(g+1) blocks starting at 2g(g+1)
    const int bid = blockIdx.x;
    int g = (int)((sqrtf(2.0f * (float)bid + 1.0f) - 1.0f) * 0.5f);
    while (2 * (g + 1) * (g + 2) <= bid) ++g;
    while (2 * g * (g + 1) > bid) --g;
    const int rem = bid - 2 * g * (g + 1);
    const int rt  = 4 * g + rem / (g + 1);
    const int js  = rem - (rem / (g + 1)) * (g + 1);

    const int rowbase = rt * 128;
    const int ntiles  = min(4, rt - 4 * js + 1);   // j-tiles in the triangle
    const bool hasdiag = (js == (rt >> 2));        // this block owns the diag tile

    const int arow0 = wr * 64;
    const int bcol0 = wc * 64;
    const f32x4 vzero = {0.0f, 0.0f, 0.0f, 0.0f};

    float rsum[16];
#pragma unroll
    for (int q = 0; q < 16; ++q) rsum[q] = 0.0f;
    float psum = 0.0f;

#pragma unroll 1
    for (int jt = 0; jt < ntiles; ++jt) {
        const int jcb = js * 512 + jt * 128;
        const bool diag = (jcb == rowbase);

        f32x4 acc[4][4];
#pragma unroll
        for (int r = 0; r < 4; ++r)
#pragma unroll
            for (int c = 0; c < 4; ++c) acc[r][c] = vzero;

#pragma unroll 1
        for (int bk = 0; bk < 4; ++bk) {
            __syncthreads();   // all waves done reading sA/sB from previous step
#pragma unroll
            for (int p = 0; p < 4; ++p) {
                const int flat = p * 4096 + t * 16;
                const int row = flat >> 7;
                const int kb  = flat & 127;
                const int skb = (kb ^ ((row & 7) << 4));
                gload16(znB + (size_t)(rowbase + row) * 512 + bk * 128 + skb, sA + flat);
                gload16(znB + (size_t)(jcb + row) * 512 + bk * 128 + skb, sB + flat);
            }
            asm volatile("s_waitcnt vmcnt(0)" ::: "memory");
            __syncthreads();
#pragma unroll
            for (int kw = 0; kw < 2; ++kw) {
                const int kt = kw * 64 + lh * 16;   // byte offset within BK chunk
                bf16x8 af[4], bfr[4];
#pragma unroll
                for (int s = 0; s < 4; ++s) {
                    const int ar = arow0 + s * 16 + lm;
                    af[s]  = *(const bf16x8*)(sA + ar * 128 + (kt ^ ((ar & 7) << 4)));
                    const int bc = bcol0 + s * 16 + lm;
                    bfr[s] = *(const bf16x8*)(sB + bc * 128 + (kt ^ ((bc & 7) << 4)));
                }
#pragma unroll
                for (int r = 0; r < 4; ++r)
#pragma unroll
                    for (int c = 0; c < 4; ++c)
                        acc[r][c] = __builtin_amdgcn_mfma_f32_16x16x32_bf16(af[r], bfr[c], acc[r][c], 0, 0, 0);
            }
        }

        // ---- per-j-tile epilogue: exp into register partials; cheap col flush only ----
        float csum[4] = {0.0f, 0.0f, 0.0f, 0.0f};
#pragma unroll
        for (int r = 0; r < 4; ++r) {
            const int ib = rowbase + arow0 + r * 16 + lh * 4;
#pragma unroll
            for (int c = 0; c < 4; ++c) {
                const int j = jcb + bcol0 + c * 16 + lm;
#pragma unroll
                for (int q = 0; q < 4; ++q) {
                    const int i = ib + q;
                    const float lg = 2.0f * acc[r][c][q];
                    const float e = __expf(lg);
                    const float ev = (diag && (j == i)) ? 0.0f : e;
                    rsum[r * 4 + q] += ev;
                    csum[c] += ev;                                   // used iff !diag
                    if (diag) psum += (j == (i ^ 1)) ? lg : 0.0f;
                }
            }
        }
        if (!diag) {
            // transposed contribution: collapse lh groups, one atomic per col (lh==0)
#pragma unroll
            for (int c = 0; c < 4; ++c) {
                float v = csum[c];
                v += __shfl_xor(v, 16); v += __shfl_xor(v, 32);
                if (lh == 0) atomicAdd(&rowsum[jcb + bcol0 + c * 16 + lm], v);
            }
        }
    }

    // ---- block-final heavy reduce (ONCE per block): rows + positives ----
#pragma unroll
    for (int q = 0; q < 16; ++q) {
        float v = rsum[q];
        v += __shfl_xor(v, 1); v += __shfl_xor(v, 2);
        v += __shfl_xor(v, 4); v += __shfl_xor(v, 8);
        rsum[q] = v;
    }
    if (lm == 0) {
#pragma unroll
        for (int r = 0; r < 4; ++r)
#pragma unroll
            for (int q = 0; q < 4; ++q)
                atomicAdd(&rowsum[rowbase + arow0 + r * 16 + lh * 4 + q], rsum[r * 4 + q]);
    }

    if (hasdiag) {
        float p = psum;
        p += __shfl_xor(p, 1);  p += __shfl_xor(p, 2);  p += __shfl_xor(p, 4);
        p += __shfl_xor(p, 8);  p += __shfl_xor(p, 16); p += __shfl_xor(p, 32);
        if (l == 0) psh[w] = p;
        __syncthreads();
        if (t == 0) atomicAdd(possum, psh[0] + psh[1] + psh[2] + psh[3]);
    }
}

// ---------------- kernel 3: final scalar ----------------
__global__ __launch_bounds__(512) void ntxent_final(const float* __restrict__ rowsum,
                                                    const float* __restrict__ possum,
                                                    float* __restrict__ out)
{
    __shared__ float sh[8];
    const int t = threadIdx.x;
    float s = 0.0f;
#pragma unroll
    for (int r = 0; r < 16; ++r) s += __logf(rowsum[r * 512 + t]);  // ILP: 16 indep loads
    s += __shfl_xor(s, 1);  s += __shfl_xor(s, 2);  s += __shfl_xor(s, 4);
    s += __shfl_xor(s, 8);  s += __shfl_xor(s, 16); s += __shfl_xor(s, 32);
    if ((t & 63) == 0) sh[t >> 6] = s;
    __syncthreads();
    if (t == 0) {
        float a = 0.0f;
#pragma unroll
        for (int k = 0; k < 8; ++k) a += sh[k];
        out[0] = (a - possum[0]) * (1.0f / NN);
    }
}

extern "C" void kernel_launch(void* const* d_in, const int* in_sizes, int n_in,
                              void* d_out, int out_size, void* d_ws, size_t ws_size,
                              hipStream_t stream)
{
    const float* z = (const float*)d_in[0];
    char*  znB    = (char*)d_ws;
    float* rowsum = (float*)((char*)d_ws + (size_t)NN * 512);
    float* possum = (float*)((char*)d_ws + (size_t)NN * 512 + (size_t)NN * 4);
    float* out = (float*)d_out;

    ntxent_norm <<<dim3(NN / 4), dim3(256), 0, stream>>>(z, znB, rowsum, possum);
    ntxent_sim  <<<dim3(544),    dim3(256), 0, stream>>>(znB, rowsum, possum);
    ntxent_final<<<dim3(1),      dim3(512), 0, stream>>>(rowsum, possum, out);
}

// Round 12
// 57.794 us; speedup vs baseline: 1.5692x; 1.0486x over previous
//
#include <hip/hip_runtime.h>

#define NN 8192
#define DD 256   // 256 bytes per fp8 row

typedef float f32x4 __attribute__((ext_vector_type(4)));

__device__ __forceinline__ void gload16(const void* g, void* l) {
    __builtin_amdgcn_global_load_lds((const __attribute__((address_space(1))) void*)g,
                                     (__attribute__((address_space(3))) void*)l,
                                     16, 0, 0);
}

// ---------------- kernel 1: normalize rows -> fp8 e4m3, zero accumulators ----------------
__global__ __launch_bounds__(256) void ntxent_norm(const float* __restrict__ z,
                                                   char* __restrict__ zn8,
                                                   float* __restrict__ rowsum,
                                                   float* __restrict__ possum)
{
    const int t = threadIdx.x;
    const int l = t & 63;
    const int w = t >> 6;
    const int row = blockIdx.x * 4 + w;

    float4 v = ((const float4*)(z + (size_t)row * DD))[l];
    float ss = v.x * v.x + v.y * v.y + v.z * v.z + v.w * v.w;
    ss += __shfl_xor(ss, 1);  ss += __shfl_xor(ss, 2);  ss += __shfl_xor(ss, 4);
    ss += __shfl_xor(ss, 8);  ss += __shfl_xor(ss, 16); ss += __shfl_xor(ss, 32);
    const float inv = 1.0f / fmaxf(sqrtf(ss), 1e-8f);

    int u = __builtin_amdgcn_cvt_pk_fp8_f32(v.x * inv, v.y * inv, 0, false);
    u     = __builtin_amdgcn_cvt_pk_fp8_f32(v.z * inv, v.w * inv, u, true);
    ((int*)(zn8 + (size_t)row * 256))[l] = u;

    if (blockIdx.x < 32) rowsum[blockIdx.x * 256 + t] = 0.0f;
    if (blockIdx.x == 32 && t == 0) possum[0] = 0.0f;
}

// ---------------- kernel 2: fp8 triangle-pruned, A-in-registers, full-K B tiles ------
// R11's (rt, js) triangle partition (544 blocks, 2080 tiles). Per block:
//   - A panel (128 rows x 256 fp8) staged once -> LDS -> af[4][8] registers/wave.
//   - Per j-tile: B panel (128 x 256 fp8 = 32 KB, FULL K) double-buffered; next tile's
//     stage issued BEFORE compute (hides under 128 MFMAs); ONE vmcnt(0)+barrier per
//     tile; zero inner barriers (K-loop is register-A x LDS-B).
// mfma_f32_16x16x32_fp8_fp8: bf16 rate, half the bytes. XOR swizzle on 16-B units
// (key row&7 in bits 4-6, same involution family as R1; b64 reads land 2 lanes/bank
// pair = free). Epilogue cadence = R11: rsum in regs across block, one heavy reduce;
// cheap per-tile col flush; diag self-mask + positives.
__global__ __launch_bounds__(256) void ntxent_sim(const char* __restrict__ zn8,
                                                  float* __restrict__ rowsum,
                                                  float* __restrict__ possum)
{
    __shared__ char sB[2][32768];   // 128 rows x 256 B, XOR-swizzled 16-B units
    __shared__ float psh[4];

    const int t  = threadIdx.x;
    const int l  = t & 63;
    const int w  = t >> 6;      // wave 0..3
    const int wr = w >> 1;      // row half
    const int wc = w & 1;       // col half
    const int lm = l & 15;
    const int lh = l >> 4;      // 0..3

    // bid -> (rt, js): band g = rt>>2 spans 4*(g+1) blocks starting at 2g(g+1)
    const int bid = blockIdx.x;
    int g = (int)((sqrtf(2.0f * (float)bid + 1.0f) - 1.0f) * 0.5f);
    while (2 * (g + 1) * (g + 2) <= bid) ++g;
    while (2 * g * (g + 1) > bid) --g;
    const int rem = bid - 2 * g * (g + 1);
    const int rt  = 4 * g + rem / (g + 1);
    const int js  = rem - (rem / (g + 1)) * (g + 1);

    const int rowbase = rt * 128;
    const int ntiles  = min(4, rt - 4 * js + 1);   // j-tiles inside the triangle
    const bool hasdiag = (js == (rt >> 2));

    const int arow0 = wr * 64;
    const int bcol0 = wc * 64;
    const f32x4 vzero = {0.0f, 0.0f, 0.0f, 0.0f};

    // stage a 128x256B fp8 panel (32 KB) into LDS buffer bp: 8 x gload16/thread
    auto STAGE = [&](char* bp, int gbase) {
#pragma unroll
        for (int p = 0; p < 8; ++p) {
            const int flat = p * 4096 + t * 16;
            const int row  = flat >> 8;                // 0..127 (256 B rows)
            const int du   = (flat >> 4) & 15;         // physical 16-B unit
            gload16(zn8 + (size_t)(gbase + row) * 256 + ((du ^ (row & 7)) << 4), bp + flat);
        }
    };

    // ---- bootstrap: A panel -> sB[0] -> af registers; B(0) -> sB[1] under the reads
    STAGE(sB[0], rowbase);
    asm volatile("s_waitcnt vmcnt(0)" ::: "memory");
    __syncthreads();

    STAGE(sB[1], js * 512);          // B(jt=0) prefetch flies under the af reads

    long af[4][8];                   // A fragments: row arow0+s*16+lm, k-chunk kw
#pragma unroll
    for (int s = 0; s < 4; ++s) {
        const int row = arow0 + s * 16 + lm;
#pragma unroll
        for (int kw = 0; kw < 8; ++kw) {
            const int u = 2 * kw + (lh >> 1);
            af[s][kw] = *(const long*)(&sB[0][row * 256 + ((u ^ (row & 7)) << 4) + ((lh & 1) << 3)]);
        }
    }
    asm volatile("s_waitcnt vmcnt(0)" ::: "memory");
    __syncthreads();                 // af read done (lgkm drained by syncthreads), B(0) visible
    int cur = 1;

    float rsum[16];
#pragma unroll
    for (int q = 0; q < 16; ++q) rsum[q] = 0.0f;
    float psum = 0.0f;

#pragma unroll 1
    for (int jt = 0; jt < ntiles; ++jt) {
        const int jcb = js * 512 + jt * 128;
        const bool diag = (jcb == rowbase);

        // prefetch next tile's B before compute (hides under the 128 MFMAs)
        if (jt + 1 < ntiles) STAGE(sB[cur ^ 1], jcb + 128);

        f32x4 acc[4][4];
#pragma unroll
        for (int r = 0; r < 4; ++r)
#pragma unroll
            for (int c = 0; c < 4; ++c) acc[r][c] = vzero;

        const char* bb = sB[cur];
#pragma unroll
        for (int kw = 0; kw < 8; ++kw) {
            long bfr[4];
#pragma unroll
            for (int c = 0; c < 4; ++c) {
                const int row = bcol0 + c * 16 + lm;
                const int u = 2 * kw + (lh >> 1);
                bfr[c] = *(const long*)(bb + row * 256 + ((u ^ (row & 7)) << 4) + ((lh & 1) << 3));
            }
#pragma unroll
            for (int r = 0; r < 4; ++r)
#pragma unroll
                for (int c = 0; c < 4; ++c)
                    acc[r][c] = __builtin_amdgcn_mfma_f32_16x16x32_fp8_fp8(af[r][kw], bfr[c], acc[r][c], 0, 0, 0);
        }

        // ---- per-j-tile epilogue: exp into register partials; cheap col flush ----
        float csum[4] = {0.0f, 0.0f, 0.0f, 0.0f};
#pragma unroll
        for (int r = 0; r < 4; ++r) {
            const int ib = rowbase + arow0 + r * 16 + lh * 4;
#pragma unroll
            for (int c = 0; c < 4; ++c) {
                const int j = jcb + bcol0 + c * 16 + lm;
#pragma unroll
                for (int q = 0; q < 4; ++q) {
                    const int i = ib + q;
                    const float lg = 2.0f * acc[r][c][q];
                    const float e = __expf(lg);
                    const float ev = (diag && (j == i)) ? 0.0f : e;
                    rsum[r * 4 + q] += ev;
                    csum[c] += ev;                                   // used iff !diag
                    if (diag) psum += (j == (i ^ 1)) ? lg : 0.0f;
                }
            }
        }
        if (!diag) {
#pragma unroll
            for (int c = 0; c < 4; ++c) {
                float v = csum[c];
                v += __shfl_xor(v, 16); v += __shfl_xor(v, 32);
                if (lh == 0) atomicAdd(&rowsum[jcb + bcol0 + c * 16 + lm], v);
            }
        }

        // drain my prefetch loads, then make next buffer visible to all waves
        asm volatile("s_waitcnt vmcnt(0)" ::: "memory");
        __syncthreads();
        cur ^= 1;
    }

    // ---- block-final heavy reduce (ONCE per block): rows + positives ----
#pragma unroll
    for (int q = 0; q < 16; ++q) {
        float v = rsum[q];
        v += __shfl_xor(v, 1); v += __shfl_xor(v, 2);
        v += __shfl_xor(v, 4); v += __shfl_xor(v, 8);
        rsum[q] = v;
    }
    if (lm == 0) {
#pragma unroll
        for (int r = 0; r < 4; ++r)
#pragma unroll
            for (int q = 0; q < 4; ++q)
                atomicAdd(&rowsum[rowbase + arow0 + r * 16 + lh * 4 + q], rsum[r * 4 + q]);
    }

    if (hasdiag) {
        float p = psum;
        p += __shfl_xor(p, 1);  p += __shfl_xor(p, 2);  p += __shfl_xor(p, 4);
        p += __shfl_xor(p, 8);  p += __shfl_xor(p, 16); p += __shfl_xor(p, 32);
        if (l == 0) psh[w] = p;
        __syncthreads();
        if (t == 0) atomicAdd(possum, psh[0] + psh[1] + psh[2] + psh[3]);
    }
}

// ---------------- kernel 3: final scalar ----------------
__global__ __launch_bounds__(512) void ntxent_final(const float* __restrict__ rowsum,
                                                    const float* __restrict__ possum,
                                                    float* __restrict__ out)
{
    __shared__ float sh[8];
    const int t = threadIdx.x;
    float s = 0.0f;
#pragma unroll
    for (int r = 0; r < 16; ++r) s += __logf(rowsum[r * 512 + t]);  // ILP: 16 indep loads
    s += __shfl_xor(s, 1);  s += __shfl_xor(s, 2);  s += __shfl_xor(s, 4);
    s += __shfl_xor(s, 8);  s += __shfl_xor(s, 16); s += __shfl_xor(s, 32);
    if ((t & 63) == 0) sh[t >> 6] = s;
    __syncthreads();
    if (t == 0) {
        float a = 0.0f;
#pragma unroll
        for (int k = 0; k < 8; ++k) a += sh[k];
        out[0] = (a - possum[0]) * (1.0f / NN);
    }
}

extern "C" void kernel_launch(void* const* d_in, const int* in_sizes, int n_in,
                              void* d_out, int out_size, void* d_ws, size_t ws_size,
                              hipStream_t stream)
{
    const float* z = (const float*)d_in[0];
    char*  zn8    = (char*)d_ws;                                      // 2 MB fp8
    float* rowsum = (float*)((char*)d_ws + (size_t)NN * 256);         // 32 KB
    float* possum = (float*)((char*)d_ws + (size_t)NN * 256 + (size_t)NN * 4);
    float* out = (float*)d_out;

    ntxent_norm <<<dim3(NN / 4), dim3(256), 0, stream>>>(z, zn8, rowsum, possum);
    ntxent_sim  <<<dim3(544),    dim3(256), 0, stream>>>(zn8, rowsum, possum);
    ntxent_final<<<dim3(1),      dim3(512), 0, stream>>>(rowsum, possum, out);
}